// Round 7
// baseline (215.819 us; speedup 1.0000x reference)
//
#include <hip/hip_runtime.h>

// ---- problem constants (from reference module) ----
constexpr float DT0      = 0.0417f;
constexpr float DENSITY_ = 1000.0f;
constexpr float DXF      = 10.0f / 125.0f;   // 0.08
constexpr float INV_DXF  = 12.5f;            // exact

// slab decomposition: WG = (m, x-slab of 2 bins, y-half of 16 rows)
constexpr int WX    = 2;              // owned x-bins per WG
constexpr int NXS   = 15;             // x-slabs (30 bins / 2)
constexpr int NYH   = 2;              // y halves
constexpr int HY    = 16;             // owned rows per half
constexpr int PLANES= 4;              // held planes  [s, s+4)
constexpr int ROWS  = 18;             // held rows    [h, h+18)
constexpr int NZ    = 32;
constexpr int NBY   = 20;             // record y-buckets (l1 in [h-2, h+18))
constexpr int NKEY  = NBY * 32;       // 640 (by_rel, z) buckets
constexpr int RCAP  = 512;            // record capacity (expected ~363)

__device__ __forceinline__ int window_min(int nf) {
    int b = 0;
    if (nf > 0) {
        b = (int)(12.5f * (float)nf - 0.5f) - 2;
        if (b < 0) b = 0;
    }
    return b;
}

// select quadratic B-spline weight for offset idx in {0,1,2}
__device__ __forceinline__ float selw(int idx, float fx) {
    const float wa = 0.5f * (1.5f - fx) * (1.5f - fx);
    const float wb = 0.75f - (fx - 1.0f) * (fx - 1.0f);
    const float wc = 0.5f * (fx - 0.5f) * (fx - 0.5f);
    return idx == 0 ? wa : (idx == 1 ? wb : wc);
}

// ================= fused: filter -> sort -> gather-P2G -> G2P -> loss ======
__global__ __launch_bounds__(256)
void fused_kernel(const float* __restrict__ x,
                  const float* __restrict__ vol,
                  const float* __restrict__ C,
                  const float* __restrict__ F,
                  const int* __restrict__ fi_p,
                  const int* __restrict__ nf_p,
                  float* __restrict__ partials,
                  int bs, int T, int Np)
{
    __shared__ float  vls[3][PLANES * ROWS * NZ];  // grid velocities, 27.6 KB
    __shared__ float4 rec[RCAP * 4];               // sorted records, 32 KB
    __shared__ int    bstart[NKEY + 1];
    __shared__ int    bcur[NKEY];
    __shared__ int    scan_tmp[256];
    __shared__ float  wsum[4];

    const int fi = fi_p[0], nf = nf_p[0];
    const int start_t = (fi == 1) ? 1 : 0;
    const int TS = (T - 2) - start_t;
    const int M  = bs * TS;
    const int wg  = blockIdx.x;
    const int m   = wg / (NXS * NYH);
    const int rem = wg - m * (NXS * NYH);
    const int s   = (rem / NYH) * WX;     // owned planes [s, s+2), held [s, s+4)
    const int h   = (rem % NYH) * HY;     // owned rows [h, h+16), cells [h, h+18)
    const int tid = threadIdx.x;
    float acc_loss = 0.0f;

    if (m < M) {
        const int b = m / TS;
        const int t = (m - b * TS) + start_t;
        const int bmin = window_min(nf);
        const float dT = DT0 * (float)fi;
        const float inv2dT = 1.0f / (2.0f * dT);
        const float nff = (float)nf;

        const float* x0s = x + (((size_t)b * T + t)     * Np) * 3;
        const float* x2s = x + (((size_t)b * T + t + 2) * Np) * 3;
        const float* Cs  = C + (((size_t)b * T + t)     * Np) * 9;
        const float* vs  = vol + (size_t)b * Np;

        // ---- pass A: histogram of region particles over (by_rel, z) ----
        for (int i = tid; i < NKEY; i += 256) bcur[i] = 0;
        __syncthreads();
        for (int n = tid; n < Np; n += 256) {
            float a0 = x0s[3*n], a1 = x0s[3*n+1], a2 = x0s[3*n+2];
            if (nf > 0) { a0 = a0*2.0f + nff; a1 = a1*2.0f + nff; a2 = a2*2.0f + nff; }
            const int l0 = (int)(a0 * INV_DXF - 0.5f) - bmin;
            const int l1 = (int)(a1 * INV_DXF - 0.5f) - bmin;
            const int l2 = (int)(a2 * INV_DXF - 0.5f) - bmin;
            if (l0 >= s-2 && l0 < s+4 && l1 >= h-2 && l1 < h+18) {
                const int key = (l1 - (h-2)) * 32 + min(max(l2, 0), 31);
                atomicAdd(&bcur[key], 1);
            }
        }
        __syncthreads();

        // ---- scan 640 buckets: thread owns 3, Hillis-Steele over 256 ----
        const int kb = tid * 3;
        int loc = 0;
#pragma unroll
        for (int q = 0; q < 3; ++q) { int kk = kb+q; if (kk < NKEY) loc += bcur[kk]; }
        scan_tmp[tid] = loc;
        __syncthreads();
        for (int off = 1; off < 256; off <<= 1) {
            int v2 = (tid >= off) ? scan_tmp[tid - off] : 0;
            __syncthreads();
            scan_tmp[tid] += v2;
            __syncthreads();
        }
        int run = scan_tmp[tid] - loc;   // exclusive prefix
#pragma unroll
        for (int q = 0; q < 3; ++q) {
            int kk = kb + q;
            if (kk < NKEY) { bstart[kk] = run; run += bcur[kk]; }
        }
        if (tid == 255) bstart[NKEY] = scan_tmp[255];
        __syncthreads();
        for (int i = tid; i < NKEY; i += 256) bcur[i] = bstart[i];
        __syncthreads();

        // ---- pass C: scatter records into sorted LDS slots ----
        for (int n = tid; n < Np; n += 256) {
            float a0 = x0s[3*n], a1 = x0s[3*n+1], a2 = x0s[3*n+2];
            if (nf > 0) { a0 = a0*2.0f + nff; a1 = a1*2.0f + nff; a2 = a2*2.0f + nff; }
            const int l0 = (int)(a0 * INV_DXF - 0.5f) - bmin;
            const int l1 = (int)(a1 * INV_DXF - 0.5f) - bmin;
            const int l2 = (int)(a2 * INV_DXF - 0.5f) - bmin;
            if (l0 >= s-2 && l0 < s+4 && l1 >= h-2 && l1 < h+18) {
                const int key = (l1 - (h-2)) * 32 + min(max(l2, 0), 31);
                const int slot = atomicAdd(&bcur[key], 1);
                if (slot < RCAP) {
                    float c0 = x2s[3*n], c1 = x2s[3*n+1], c2 = x2s[3*n+2];
                    if (nf > 0) { c0 = c0*2.0f + nff; c1 = c1*2.0f + nff; c2 = c2*2.0f + nff; }
                    rec[slot*4+0] = make_float4(a0, a1, a2, DENSITY_ * vs[n]);
                    rec[slot*4+1] = make_float4((c0-a0)*inv2dT, (c1-a1)*inv2dT,
                                                (c2-a2)*inv2dT, Cs[9*n+8]);
                    rec[slot*4+2] = make_float4(Cs[9*n+0], Cs[9*n+1], Cs[9*n+2], Cs[9*n+3]);
                    rec[slot*4+3] = make_float4(Cs[9*n+4], Cs[9*n+5], Cs[9*n+6], Cs[9*n+7]);
                }
            }
        }
        __syncthreads();

        // ---- gather-P2G: each lane owns cells (plane pr, rows rh+2r, col lk) ----
        // cell sums accumulate in registers; normalize; store velocity to LDS.
        {
            const int pr   = tid >> 6;       // 0..3
            const int lane = tid & 63;
            const int lk   = lane & 31;
            const int rh   = lane >> 5;      // 0/1
            const int li   = s + pr;
            const int zlo  = max(lk - 2, 0);
            const int zhi  = min(lk, 31);
            for (int rr = 0; rr < 9; ++rr) {
                const int row = rh + 2*rr;   // 0..17
                float ax = 0.f, ay = 0.f, az = 0.f, am = 0.f;
#pragma unroll
                for (int byo = 0; byo < 3; ++byo) {
                    const int byr = row + byo;         // by_rel; j = 2 - byo
                    const int j   = 2 - byo;
                    int rs = bstart[byr*32 + zlo];
                    int re = bstart[byr*32 + zhi + 1];
                    rs = min(rs, RCAP); re = min(re, RCAP);
                    for (int q = rs; q < re; ++q) {
                        const float4 r0 = rec[q*4+0];
                        const float gp0 = r0.x * INV_DXF;
                        const int   b0  = (int)(gp0 - 0.5f);
                        const int   i   = li - (b0 - bmin);
                        if ((unsigned)i > 2u) continue;
                        const float fx0 = gp0 - (float)b0;
                        const float gp1 = r0.y * INV_DXF;
                        const int   b1  = (int)(gp1 - 0.5f);
                        const float fx1 = gp1 - (float)b1;
                        const float gp2 = r0.z * INV_DXF;
                        const int   b2  = (int)(gp2 - 0.5f);
                        const float fx2 = gp2 - (float)b2;
                        const int   k   = lk - (b2 - bmin);   // in [0,2] by range
                        const float mw  = r0.w * selw(i,fx0) * selw(j,fx1) * selw(k,fx2);
                        const float4 r1 = rec[q*4+1];
                        const float4 r2 = rec[q*4+2];
                        const float4 r3 = rec[q*4+3];
                        const float dpx = ((float)i - fx0) * DXF;
                        const float dpy = ((float)j - fx1) * DXF;
                        const float dpz = ((float)k - fx2) * DXF;
                        const float vx = r1.x + r2.x*dpx + r2.y*dpy + r2.z*dpz;
                        const float vy = r1.y + r2.w*dpx + r3.x*dpy + r3.y*dpz;
                        const float vz = r1.z + r3.z*dpx + r3.w*dpy + r1.w*dpz;
                        ax += mw*vx; ay += mw*vy; az += mw*vz; am += mw;
                    }
                }
                const float inv = (am > 1e-15f) ? 1.0f / am : 1.0f;
                const int cell = (pr * ROWS + row) * NZ + lk;
                vls[0][cell] = ax * inv;
                vls[1][cell] = ay * inv;
                vls[2][cell] = az * inv;
            }
        }
        __syncthreads();

        // ---- G2P + loss over owned particles (rescan global x) ----
        const float scale = (float)TS / ((float)M * (float)Np * 9.0f);
        for (int n = tid; n < Np; n += 256) {
            float a0 = x0s[3*n], a1 = x0s[3*n+1], a2 = x0s[3*n+2];
            if (nf > 0) { a0 = a0*2.0f + nff; a1 = a1*2.0f + nff; a2 = a2*2.0f + nff; }
            const float gp0 = a0 * INV_DXF;
            const int   b0  = (int)(gp0 - 0.5f);
            const float gp1 = a1 * INV_DXF;
            const int   b1  = (int)(gp1 - 0.5f);
            const float gp2 = a2 * INV_DXF;
            const int   b2  = (int)(gp2 - 0.5f);
            const int l0 = b0 - bmin, l1 = b1 - bmin, l2 = b2 - bmin;
            if (l0 < s || l0 >= s + WX || l1 < h || l1 >= h + HY) continue;

            const float fx[3] = {gp0 - (float)b0, gp1 - (float)b1, gp2 - (float)b2};
            float w[3][3], dw[3][3];
#pragma unroll
            for (int d = 0; d < 3; ++d) {
                w[d][0] = 0.5f * (1.5f - fx[d]) * (1.5f - fx[d]);
                w[d][1] = 0.75f - (fx[d] - 1.0f) * (fx[d] - 1.0f);
                w[d][2] = 0.5f * (fx[d] - 0.5f) * (fx[d] - 0.5f);
                dw[d][0] = fx[d] - 1.5f;
                dw[d][1] = -2.0f * (fx[d] - 1.0f);
                dw[d][2] = fx[d] - 0.5f;
            }

            float nF[9] = {0,0,0,0,0,0,0,0,0};
            const int prb = l0 - s, rwb = l1 - h;
#pragma unroll
            for (int i = 0; i < 3; ++i) {
#pragma unroll
                for (int j = 0; j < 3; ++j) {
                    const int rbase = ((prb + i) * ROWS + (rwb + j)) * NZ + l2;
                    const float wij  = w[0][i] * w[1][j];
                    const float dwxp = dw[0][i] * w[1][j];
                    const float dwyp = w[0][i] * dw[1][j];
#pragma unroll
                    for (int k = 0; k < 3; ++k) {
                        const int cell = rbase + k;
                        const float gx = vls[0][cell], gy = vls[1][cell], gz = vls[2][cell];
                        const float dwx = dwxp * w[2][k] * INV_DXF;
                        const float dwy = dwyp * w[2][k] * INV_DXF;
                        const float dwz = wij * dw[2][k] * INV_DXF;
                        nF[0] += gx*dwx; nF[1] += gx*dwy; nF[2] += gx*dwz;
                        nF[3] += gy*dwx; nF[4] += gy*dwy; nF[5] += gy*dwz;
                        nF[6] += gz*dwx; nF[7] += gz*dwy; nF[8] += gz*dwz;
                    }
                }
            }

            const float* pF  = F + (((size_t)b * T + t)     * Np + n) * 9;
            const float* pFn = F + (((size_t)b * T + t + 1) * Np + n) * 9;
            float Fm[9], Fn[9];
#pragma unroll
            for (int i = 0; i < 9; ++i) { Fm[i] = pF[i]; Fn[i] = pFn[i]; }
            float ls = 0.0f;
#pragma unroll
            for (int aa = 0; aa < 3; ++aa) {
#pragma unroll
                for (int cc = 0; cc < 3; ++cc) {
                    const float fp = Fm[aa*3 + cc] + dT *
                        (nF[aa*3 + 0] * Fm[0 + cc] +
                         nF[aa*3 + 1] * Fm[3 + cc] +
                         nF[aa*3 + 2] * Fm[6 + cc]);
                    ls += fabsf(fp - Fn[aa*3 + cc]);
                }
            }
            acc_loss += ls * scale;
        }
    }

    // ---- block reduction -> per-block partial (plain store) ----
#pragma unroll
    for (int o = 32; o > 0; o >>= 1) acc_loss += __shfl_down(acc_loss, o, 64);
    const int lane = tid & 63;
    const int wid  = tid >> 6;
    if (lane == 0) wsum[wid] = acc_loss;
    __syncthreads();
    if (tid == 0)
        partials[blockIdx.x] = wsum[0] + wsum[1] + wsum[2] + wsum[3];
}

// ================= final reduce ============================================
__global__ __launch_bounds__(256)
void reduce_kernel(const float* __restrict__ partials, int n,
                   float* __restrict__ out)
{
    float s = 0.0f;
    for (int i = threadIdx.x; i < n; i += 256) s += partials[i];
#pragma unroll
    for (int o = 32; o > 0; o >>= 1) s += __shfl_down(s, o, 64);
    __shared__ float wsum[4];
    const int lane = threadIdx.x & 63;
    const int wid  = threadIdx.x >> 6;
    if (lane == 0) wsum[wid] = s;
    __syncthreads();
    if (threadIdx.x == 0) out[0] = wsum[0] + wsum[1] + wsum[2] + wsum[3];
}

extern "C" void kernel_launch(void* const* d_in, const int* in_sizes, int n_in,
                              void* d_out, int out_size, void* d_ws, size_t ws_size,
                              hipStream_t stream) {
    const float* x   = (const float*)d_in[0];
    const float* vol = (const float*)d_in[1];
    const float* F   = (const float*)d_in[2];
    const float* C   = (const float*)d_in[3];
    const int*   fi  = (const int*)d_in[4];
    const int*   nf  = (const int*)d_in[5];

    const int Np = 2048;
    const int bs = in_sizes[1] / Np;                 // 2
    const int T  = in_sizes[0] / (bs * Np * 3);      // 16
    const int MMAX = bs * (T - 2);                   // 28

    float* partials = (float*)d_ws;                  // only ws use: 840 floats

    const int nfb = MMAX * NXS * NYH;                // 840
    fused_kernel<<<nfb, 256, 0, stream>>>(x, vol, C, F, fi, nf,
                                          partials, bs, T, Np);
    reduce_kernel<<<1, 256, 0, stream>>>(partials, nfb, (float*)d_out);
}

// Round 8
// 134.875 us; speedup vs baseline: 1.6001x; 1.6001x over previous
//
#include <hip/hip_runtime.h>

// ---- problem constants (from reference module) ----
constexpr float DT0      = 0.0417f;
constexpr float DENSITY_ = 1000.0f;
constexpr float DXF      = 10.0f / 125.0f;   // 0.08
constexpr float INV_DXF  = 12.5f;            // exact

constexpr int DIM  = 32;
constexpr int DIM2 = DIM * DIM;
constexpr int DIM3 = DIM * DIM * DIM;

__device__ __forceinline__ int window_min(int nf) {
    int b = 0;
    if (nf > 0) {
        b = (int)(12.5f * (float)nf - 0.5f) - 2;
        if (b < 0) b = 0;
    }
    return b;
}

// ---------------- P2G: (m, x-plane) WG of 1024 threads, 4 private LDS copies
// Quarter q (4 waves) accumulates its 512-particle range into copy q
// (shorter DS bank queues, no cross-quarter contention), then merge + store.
// 64 KB LDS -> 2 WGs/CU -> 32 waves/CU (full occupancy).
__global__ __launch_bounds__(1024)
void p2g_kernel(const float* __restrict__ x,
                const float* __restrict__ vol,
                const float* __restrict__ C,
                const int* __restrict__ fi_p,
                const int* __restrict__ nf_p,
                float* __restrict__ grid,
                int bs, int T, int Np)
{
    __shared__ float pl[4][DIM2 * 4];   // 4 copies x 16 KB (AoS float4 per cell)

    const int fi = fi_p[0], nf = nf_p[0];
    const int start_t = (fi == 1) ? 1 : 0;
    const int TS = (T - 2) - start_t;
    const int M  = bs * TS;

    const int m   = blockIdx.x >> 5;
    const int p   = blockIdx.x & (DIM - 1);
    const int tid = threadIdx.x;
    const int q   = tid >> 8;          // quarter 0..3 (4 waves each)
    const int lt  = tid & 255;

    float* plf = &pl[0][0];
    for (int i = tid; i < 4 * DIM2 * 4; i += 1024) plf[i] = 0.0f;
    __syncthreads();

    if (m < M) {
        const int b = m / TS;
        const int t = (m - b * TS) + start_t;
        const int bmin = window_min(nf);
        const float dT = DT0 * (float)fi;
        const float inv2dT = 1.0f / (2.0f * dT);
        const float nff = (float)nf;

        const float* x0s = x + (((size_t)b * T + t)     * Np) * 3;
        const float* x2s = x + (((size_t)b * T + t + 2) * Np) * 3;
        const float* Cs  = C + (((size_t)b * T + t)     * Np) * 9;
        const float* vs  = vol + (size_t)b * Np;

        float* myp = pl[q];
        const int nbeg = q * (Np >> 2);
        const int nend = nbeg + (Np >> 2);

        for (int n = nbeg + lt; n < nend; n += 256) {
            // filter on x-coordinate
            float a0 = x0s[3 * n];
            if (nf > 0) a0 = a0 * 2.0f + nff;
            const float gp0 = a0 * INV_DXF;
            const int b0 = (int)(gp0 - 0.5f);
            const int l0 = b0 - bmin;
            const int lo = min(max(l0, 0), DIM - 1);
            const int hi = min(max(l0 + 2, 0), DIM - 1);
            if (p < lo || p > hi) continue;

            float a1 = x0s[3 * n + 1], a2 = x0s[3 * n + 2];
            float c0 = x2s[3 * n], c1 = x2s[3 * n + 1], c2 = x2s[3 * n + 2];
            if (nf > 0) {
                a1 = a1 * 2.0f + nff; a2 = a2 * 2.0f + nff;
                c0 = c0 * 2.0f + nff; c1 = c1 * 2.0f + nff; c2 = c2 * 2.0f + nff;
            }
            const float pv0 = (c0 - a0) * inv2dT;
            const float pv1 = (c1 - a1) * inv2dT;
            const float pv2 = (c2 - a2) * inv2dT;
            const float mass = DENSITY_ * vs[n];
            float Cm[9];
#pragma unroll
            for (int r = 0; r < 9; ++r) Cm[r] = Cs[9 * n + r];

            const float fx0 = gp0 - (float)b0;
            const float gp1 = a1 * INV_DXF;
            const int   b1  = (int)(gp1 - 0.5f);
            const float fx1 = gp1 - (float)b1;
            const float gp2 = a2 * INV_DXF;
            const int   b2  = (int)(gp2 - 0.5f);
            const float fx2 = gp2 - (float)b2;
            const int l1 = b1 - bmin, l2 = b2 - bmin;

            float w0[3], w1[3], w2[3];
            w0[0] = 0.5f * (1.5f - fx0) * (1.5f - fx0);
            w0[1] = 0.75f - (fx0 - 1.0f) * (fx0 - 1.0f);
            w0[2] = 0.5f * (fx0 - 0.5f) * (fx0 - 0.5f);
            w1[0] = 0.5f * (1.5f - fx1) * (1.5f - fx1);
            w1[1] = 0.75f - (fx1 - 1.0f) * (fx1 - 1.0f);
            w1[2] = 0.5f * (fx1 - 0.5f) * (fx1 - 0.5f);
            w2[0] = 0.5f * (1.5f - fx2) * (1.5f - fx2);
            w2[1] = 0.75f - (fx2 - 1.0f) * (fx2 - 1.0f);
            w2[2] = 0.5f * (fx2 - 0.5f) * (fx2 - 0.5f);

#pragma unroll
            for (int i = 0; i < 3; ++i) {
                const int li = min(max(l0 + i, 0), DIM - 1);
                if (li != p) continue;
                const float dpx = ((float)i - fx0) * DXF;
                const float wi  = w0[i];
#pragma unroll
                for (int j = 0; j < 3; ++j) {
                    const int lj = min(max(l1 + j, 0), DIM - 1);
                    const float wij = wi * w1[j];
                    const float dpy = ((float)j - fx1) * DXF;
#pragma unroll
                    for (int k = 0; k < 3; ++k) {
                        const int lk = min(max(l2 + k, 0), DIM - 1);
                        const float mw  = mass * wij * w2[k];
                        const float dpz = ((float)k - fx2) * DXF;
                        const float vx = pv0 + Cm[0]*dpx + Cm[1]*dpy + Cm[2]*dpz;
                        const float vy = pv1 + Cm[3]*dpx + Cm[4]*dpy + Cm[5]*dpz;
                        const float vz = pv2 + Cm[6]*dpx + Cm[7]*dpy + Cm[8]*dpz;
                        float* cell = myp + (lj * DIM + lk) * 4;
                        atomicAdd(cell + 0, mw * vx);
                        atomicAdd(cell + 1, mw * vy);
                        atomicAdd(cell + 2, mw * vz);
                        atomicAdd(cell + 3, mw);
                    }
                }
            }
        }
    }
    __syncthreads();

    // merge 4 copies + coalesced writeback
    if (m < M) {
        const float4* c0 = (const float4*)pl[0];
        const float4* c1 = (const float4*)pl[1];
        const float4* c2 = (const float4*)pl[2];
        const float4* c3 = (const float4*)pl[3];
        float4* dst = (float4*)(grid + ((size_t)m * DIM + p) * DIM2 * 4);
        for (int cell = tid; cell < DIM2; cell += 1024) {
            const float4 a = c0[cell], bb = c1[cell], cc = c2[cell], dd = c3[cell];
            dst[cell] = make_float4(a.x + bb.x + cc.x + dd.x,
                                    a.y + bb.y + cc.y + dd.y,
                                    a.z + bb.z + cc.z + dd.z,
                                    a.w + bb.w + cc.w + dd.w);
        }
    }
}

// ---------------- G2P + loss: 4 lanes per particle; per-block partials -----
__global__ __launch_bounds__(256)
void g2p_loss_kernel(const float* __restrict__ x,
                     const float* __restrict__ F,
                     const int* __restrict__ fi_p,
                     const int* __restrict__ nf_p,
                     const float* __restrict__ grid,
                     float* __restrict__ partials,
                     int bs, int T, int Np)
{
    const int fi = fi_p[0], nf = nf_p[0];
    const int start_t = (fi == 1) ? 1 : 0;
    const int TS = (T - 2) - start_t;
    const int M  = bs * TS;
    const float dT = DT0 * (float)fi;

    const int gid = blockIdx.x * blockDim.x + threadIdx.x;
    const int pid = gid >> 2;      // particle slot
    const int q   = gid & 3;       // sub-lane 0..3
    float s = 0.0f;

    if (pid < M * Np) {
        const int m = pid / Np;
        const int n = pid - m * Np;
        const int b = m / TS;
        const int t = (m - b * TS) + start_t;
        const float nff = (float)nf;

        const float* x0 = x + (((size_t)b * T + t) * Np + n) * 3;
        float px[3];
#pragma unroll
        for (int d = 0; d < 3; ++d) {
            float a0 = x0[d];
            if (nf > 0) a0 = a0 * 2.0f + nff;
            px[d] = a0;
        }

        const int bmin = window_min(nf);
        int   base[3];
        float fx[3], w[3][3], dw[3][3];
#pragma unroll
        for (int d = 0; d < 3; ++d) {
            const float gp = px[d] * INV_DXF;
            base[d] = (int)(gp - 0.5f);
            fx[d]   = gp - (float)base[d];
            w[d][0] = 0.5f * (1.5f - fx[d]) * (1.5f - fx[d]);
            w[d][1] = 0.75f - (fx[d] - 1.0f) * (fx[d] - 1.0f);
            w[d][2] = 0.5f * (fx[d] - 0.5f) * (fx[d] - 0.5f);
            dw[d][0] = fx[d] - 1.5f;
            dw[d][1] = -2.0f * (fx[d] - 1.0f);
            dw[d][2] = fx[d] - 0.5f;
        }

        const float* gbase = grid + (size_t)m * DIM3 * 4;
        float nF[9] = {0,0,0,0,0,0,0,0,0};
#pragma unroll
        for (int o = q; o < 27; o += 4) {
            const int i = o / 9, j = (o / 3) % 3, k = o % 3;
            const int li = min(max(base[0] + i - bmin, 0), DIM - 1);
            const int lj = min(max(base[1] + j - bmin, 0), DIM - 1);
            const int lk = min(max(base[2] + k - bmin, 0), DIM - 1);
            const float4 g = *(const float4*)(gbase +
                ((size_t)((li * DIM + lj) * DIM + lk)) * 4);
            const float gm  = (g.w > 1e-15f) ? g.w : 1.0f;
            const float inv = 1.0f / gm;
            const float gx = g.x * inv, gy = g.y * inv, gz = g.z * inv;
            const float dwx = dw[0][i] *  w[1][j] *  w[2][k] * INV_DXF;
            const float dwy =  w[0][i] * dw[1][j] *  w[2][k] * INV_DXF;
            const float dwz =  w[0][i] *  w[1][j] * dw[2][k] * INV_DXF;
            nF[0] += gx * dwx; nF[1] += gx * dwy; nF[2] += gx * dwz;
            nF[3] += gy * dwx; nF[4] += gy * dwy; nF[5] += gy * dwz;
            nF[6] += gz * dwx; nF[7] += gz * dwy; nF[8] += gz * dwz;
        }
        // butterfly reduce across the particle's 4 lanes
#pragma unroll
        for (int d = 1; d < 4; d <<= 1) {
#pragma unroll
            for (int r = 0; r < 9; ++r) nF[r] += __shfl_xor(nF[r], d, 64);
        }

        if (q == 0) {
            const float* pF  = F + (((size_t)b * T + t)     * Np + n) * 9;
            const float* pFn = F + (((size_t)b * T + t + 1) * Np + n) * 9;
            float Fm[9], Fn[9];
#pragma unroll
            for (int i = 0; i < 9; ++i) { Fm[i] = pF[i]; Fn[i] = pFn[i]; }
#pragma unroll
            for (int a = 0; a < 3; ++a) {
#pragma unroll
                for (int c = 0; c < 3; ++c) {
                    const float fp = Fm[a * 3 + c] + dT *
                        (nF[a * 3 + 0] * Fm[0 + c] +
                         nF[a * 3 + 1] * Fm[3 + c] +
                         nF[a * 3 + 2] * Fm[6 + c]);
                    s += fabsf(fp - Fn[a * 3 + c]);
                }
            }
            s *= (float)TS / ((float)M * (float)Np * 9.0f);
        }
    }

    // block reduction -> per-block partial (plain store)
#pragma unroll
    for (int o = 32; o > 0; o >>= 1) s += __shfl_down(s, o, 64);
    __shared__ float wsum[4];
    const int lane = threadIdx.x & 63;
    const int wid  = threadIdx.x >> 6;
    if (lane == 0) wsum[wid] = s;
    __syncthreads();
    if (threadIdx.x == 0)
        partials[blockIdx.x] = wsum[0] + wsum[1] + wsum[2] + wsum[3];
}

// ---------------- final reduce ---------------------------------------------
__global__ __launch_bounds__(256)
void reduce_kernel(const float* __restrict__ partials, int n,
                   float* __restrict__ out)
{
    float s = 0.0f;
    for (int i = threadIdx.x; i < n; i += 256) s += partials[i];
#pragma unroll
    for (int o = 32; o > 0; o >>= 1) s += __shfl_down(s, o, 64);
    __shared__ float wsum[4];
    const int lane = threadIdx.x & 63;
    const int wid  = threadIdx.x >> 6;
    if (lane == 0) wsum[wid] = s;
    __syncthreads();
    if (threadIdx.x == 0) out[0] = wsum[0] + wsum[1] + wsum[2] + wsum[3];
}

extern "C" void kernel_launch(void* const* d_in, const int* in_sizes, int n_in,
                              void* d_out, int out_size, void* d_ws, size_t ws_size,
                              hipStream_t stream) {
    const float* x   = (const float*)d_in[0];
    const float* vol = (const float*)d_in[1];
    const float* F   = (const float*)d_in[2];
    const float* C   = (const float*)d_in[3];
    const int*   fi  = (const int*)d_in[4];
    const int*   nf  = (const int*)d_in[5];

    const int Np = 2048;
    const int bs = in_sizes[1] / Np;                 // 2
    const int T  = in_sizes[0] / (bs * Np * 3);      // 16
    const int MMAX = bs * (T - 2);                   // 28

    float* grid = (float*)d_ws;
    const size_t grid_f = (size_t)MMAX * DIM3 * 4;   // 14.68 MB
    float* partials = grid + grid_f;

    // P2G: 1024-thread WGs, 4 private LDS copies, full occupancy
    p2g_kernel<<<MMAX * DIM, 1024, 0, stream>>>(x, vol, C, fi, nf,
                                                grid, bs, T, Np);

    // G2P: 4 lanes per particle, per-block partials
    const int nthreads = MMAX * Np * 4;
    const int nblocks  = (nthreads + 255) / 256;     // 3584
    g2p_loss_kernel<<<nblocks, 256, 0, stream>>>(
        x, F, fi, nf, grid, partials, bs, T, Np);

    reduce_kernel<<<1, 256, 0, stream>>>(partials, nblocks, (float*)d_out);
}

// Round 10
// 121.792 us; speedup vs baseline: 1.7720x; 1.1074x over previous
//
#include <hip/hip_runtime.h>
#include <hip/hip_fp16.h>

// ---- problem constants (from reference module) ----
constexpr float DT0      = 0.0417f;
constexpr float DENSITY_ = 1000.0f;
constexpr float DXF      = 10.0f / 125.0f;   // 0.08
constexpr float INV_DXF  = 12.5f;            // exact

constexpr int DIM  = 32;
constexpr int DIM2 = DIM * DIM;
constexpr int DIM3 = DIM * DIM * DIM;

constexpr float MSC  = 1.0f / 16.0f;   // momentum pre-scale (f16 overflow headroom)
constexpr float IMSC = 16.0f;

typedef _Float16 f16x2 __attribute__((ext_vector_type(2)));

// packed f16x2 LDS atomic add: 1 DS lane-op for 2 components.
__device__ __forceinline__ void lds_pk_fadd(f16x2* addr, float lo, float hi) {
    f16x2 v;
    v.x = (_Float16)lo;
    v.y = (_Float16)hi;
#if __has_builtin(__builtin_amdgcn_ds_atomic_fadd_v2f16)
    (void)__builtin_amdgcn_ds_atomic_fadd_v2f16(
        (__attribute__((address_space(3))) f16x2*)addr, v);
#else
    // CAS fallback (correct on any arch; only used if the builtin is absent)
    unsigned int* ua = (unsigned int*)addr;
    union { f16x2 h; unsigned int u; } oldv, newv, cur;
    cur.u = __atomic_load_n(ua, __ATOMIC_RELAXED);
    do {
        oldv.u = cur.u;
        newv.h = oldv.h + v;
        cur.u  = atomicCAS(ua, oldv.u, newv.u);
    } while (cur.u != oldv.u);
#endif
}

__device__ __forceinline__ int window_min(int nf) {
    int b = 0;
    if (nf > 0) {
        b = (int)(12.5f * (float)nf - 0.5f) - 2;
        if (b < 0) b = 0;
    }
    return b;
}

// ---------------- P2G: (m, x-plane) WG of 1024 threads, 4 private LDS copies.
// f16x2 packed LDS atomics (ds_pk_add_f16): 2 lane-ops per cell-contribution
// instead of 4 — the DS pipe retires atomics lane-serially (~5.5 cyc/lane,
// fitted across R2/R3/R4/R8), so halving the count should halve p2g.
// Writeback merges the 4 copies in f32, normalizes (mass guard), and stores a
// float4 VELOCITY grid (g2p no longer divides).
__global__ __launch_bounds__(1024)
void p2g_kernel(const float* __restrict__ x,
                const float* __restrict__ vol,
                const float* __restrict__ C,
                const int* __restrict__ fi_p,
                const int* __restrict__ nf_p,
                float* __restrict__ grid,
                int bs, int T, int Np)
{
    // pl[q][cell*2+0] = (mom.x, mom.y)*MSC ; pl[q][cell*2+1] = (mom.z*MSC, mass)
    __shared__ f16x2 pl[4][DIM2 * 2];   // 4 copies x 4 KB

    const int fi = fi_p[0], nf = nf_p[0];
    const int start_t = (fi == 1) ? 1 : 0;
    const int TS = (T - 2) - start_t;
    const int M  = bs * TS;

    const int m   = blockIdx.x >> 5;
    const int p   = blockIdx.x & (DIM - 1);
    const int tid = threadIdx.x;
    const int q   = tid >> 8;          // quarter 0..3 (4 waves each)
    const int lt  = tid & 255;

    f16x2* plf = &pl[0][0];
    f16x2 hz; hz.x = (_Float16)0.0f; hz.y = (_Float16)0.0f;
    for (int i = tid; i < 4 * DIM2 * 2; i += 1024) plf[i] = hz;
    __syncthreads();

    if (m < M) {
        const int b = m / TS;
        const int t = (m - b * TS) + start_t;
        const int bmin = window_min(nf);
        const float dT = DT0 * (float)fi;
        const float inv2dT = 1.0f / (2.0f * dT);
        const float nff = (float)nf;

        const float* x0s = x + (((size_t)b * T + t)     * Np) * 3;
        const float* x2s = x + (((size_t)b * T + t + 2) * Np) * 3;
        const float* Cs  = C + (((size_t)b * T + t)     * Np) * 9;
        const float* vs  = vol + (size_t)b * Np;

        f16x2* myp = pl[q];
        const int nbeg = q * (Np >> 2);
        const int nend = nbeg + (Np >> 2);

        for (int n = nbeg + lt; n < nend; n += 256) {
            // filter on x-coordinate
            float a0 = x0s[3 * n];
            if (nf > 0) a0 = a0 * 2.0f + nff;
            const float gp0 = a0 * INV_DXF;
            const int b0 = (int)(gp0 - 0.5f);
            const int l0 = b0 - bmin;
            const int lo = min(max(l0, 0), DIM - 1);
            const int hi = min(max(l0 + 2, 0), DIM - 1);
            if (p < lo || p > hi) continue;

            float a1 = x0s[3 * n + 1], a2 = x0s[3 * n + 2];
            float c0 = x2s[3 * n], c1 = x2s[3 * n + 1], c2 = x2s[3 * n + 2];
            if (nf > 0) {
                a1 = a1 * 2.0f + nff; a2 = a2 * 2.0f + nff;
                c0 = c0 * 2.0f + nff; c1 = c1 * 2.0f + nff; c2 = c2 * 2.0f + nff;
            }
            const float pv0 = (c0 - a0) * inv2dT;
            const float pv1 = (c1 - a1) * inv2dT;
            const float pv2 = (c2 - a2) * inv2dT;
            const float mass = DENSITY_ * vs[n];
            float Cm[9];
#pragma unroll
            for (int r = 0; r < 9; ++r) Cm[r] = Cs[9 * n + r];

            const float fx0 = gp0 - (float)b0;
            const float gp1 = a1 * INV_DXF;
            const int   b1  = (int)(gp1 - 0.5f);
            const float fx1 = gp1 - (float)b1;
            const float gp2 = a2 * INV_DXF;
            const int   b2  = (int)(gp2 - 0.5f);
            const float fx2 = gp2 - (float)b2;
            const int l1 = b1 - bmin, l2 = b2 - bmin;

            float w0[3], w1[3], w2[3];
            w0[0] = 0.5f * (1.5f - fx0) * (1.5f - fx0);
            w0[1] = 0.75f - (fx0 - 1.0f) * (fx0 - 1.0f);
            w0[2] = 0.5f * (fx0 - 0.5f) * (fx0 - 0.5f);
            w1[0] = 0.5f * (1.5f - fx1) * (1.5f - fx1);
            w1[1] = 0.75f - (fx1 - 1.0f) * (fx1 - 1.0f);
            w1[2] = 0.5f * (fx1 - 0.5f) * (fx1 - 0.5f);
            w2[0] = 0.5f * (1.5f - fx2) * (1.5f - fx2);
            w2[1] = 0.75f - (fx2 - 1.0f) * (fx2 - 1.0f);
            w2[2] = 0.5f * (fx2 - 0.5f) * (fx2 - 0.5f);

#pragma unroll
            for (int i = 0; i < 3; ++i) {
                const int li = min(max(l0 + i, 0), DIM - 1);
                if (li != p) continue;
                const float dpx = ((float)i - fx0) * DXF;
                const float wi  = w0[i];
#pragma unroll
                for (int j = 0; j < 3; ++j) {
                    const int lj = min(max(l1 + j, 0), DIM - 1);
                    const float wij = wi * w1[j];
                    const float dpy = ((float)j - fx1) * DXF;
#pragma unroll
                    for (int k = 0; k < 3; ++k) {
                        const int lk = min(max(l2 + k, 0), DIM - 1);
                        const float mw  = mass * wij * w2[k];
                        const float dpz = ((float)k - fx2) * DXF;
                        const float vx = pv0 + Cm[0]*dpx + Cm[1]*dpy + Cm[2]*dpz;
                        const float vy = pv1 + Cm[3]*dpx + Cm[4]*dpy + Cm[5]*dpz;
                        const float vz = pv2 + Cm[6]*dpx + Cm[7]*dpy + Cm[8]*dpz;
                        const int cell = lj * DIM + lk;
                        lds_pk_fadd(&myp[cell * 2 + 0], mw * vx * MSC, mw * vy * MSC);
                        lds_pk_fadd(&myp[cell * 2 + 1], mw * vz * MSC, mw);
                    }
                }
            }
        }
    }
    __syncthreads();

    // merge 4 copies in f32, normalize, write velocity grid (coalesced)
    if (m < M) {
        float4* dst = (float4*)(grid + ((size_t)m * DIM + p) * DIM2 * 4);
        for (int cell = tid; cell < DIM2; cell += 1024) {
            float mx = 0.f, my = 0.f, mz = 0.f, gm = 0.f;
#pragma unroll
            for (int cp = 0; cp < 4; ++cp) {
                const f16x2 s0 = pl[cp][cell * 2 + 0];
                const f16x2 s1 = pl[cp][cell * 2 + 1];
                mx += (float)s0.x; my += (float)s0.y;
                mz += (float)s1.x; gm += (float)s1.y;
            }
            const float inv = (gm > 1e-15f) ? IMSC / gm : IMSC;
            dst[cell] = make_float4(mx * inv, my * inv, mz * inv, 0.0f);
        }
    }
}

// ---------------- G2P + loss: 4 lanes per particle; grid holds velocities --
__global__ __launch_bounds__(256)
void g2p_loss_kernel(const float* __restrict__ x,
                     const float* __restrict__ F,
                     const int* __restrict__ fi_p,
                     const int* __restrict__ nf_p,
                     const float* __restrict__ grid,
                     float* __restrict__ partials,
                     int bs, int T, int Np)
{
    const int fi = fi_p[0], nf = nf_p[0];
    const int start_t = (fi == 1) ? 1 : 0;
    const int TS = (T - 2) - start_t;
    const int M  = bs * TS;
    const float dT = DT0 * (float)fi;

    const int gid = blockIdx.x * blockDim.x + threadIdx.x;
    const int pid = gid >> 2;      // particle slot
    const int q   = gid & 3;       // sub-lane 0..3
    float s = 0.0f;

    if (pid < M * Np) {
        const int m = pid / Np;
        const int n = pid - m * Np;
        const int b = m / TS;
        const int t = (m - b * TS) + start_t;
        const float nff = (float)nf;

        const float* x0 = x + (((size_t)b * T + t) * Np + n) * 3;
        float px[3];
#pragma unroll
        for (int d = 0; d < 3; ++d) {
            float a0 = x0[d];
            if (nf > 0) a0 = a0 * 2.0f + nff;
            px[d] = a0;
        }

        const int bmin = window_min(nf);
        int   base[3];
        float fx[3], w[3][3], dw[3][3];
#pragma unroll
        for (int d = 0; d < 3; ++d) {
            const float gp = px[d] * INV_DXF;
            base[d] = (int)(gp - 0.5f);
            fx[d]   = gp - (float)base[d];
            w[d][0] = 0.5f * (1.5f - fx[d]) * (1.5f - fx[d]);
            w[d][1] = 0.75f - (fx[d] - 1.0f) * (fx[d] - 1.0f);
            w[d][2] = 0.5f * (fx[d] - 0.5f) * (fx[d] - 0.5f);
            dw[d][0] = fx[d] - 1.5f;
            dw[d][1] = -2.0f * (fx[d] - 1.0f);
            dw[d][2] = fx[d] - 0.5f;
        }

        const float* gbase = grid + (size_t)m * DIM3 * 4;
        float nF[9] = {0,0,0,0,0,0,0,0,0};
#pragma unroll
        for (int o = q; o < 27; o += 4) {
            const int i = o / 9, j = (o / 3) % 3, k = o % 3;
            const int li = min(max(base[0] + i - bmin, 0), DIM - 1);
            const int lj = min(max(base[1] + j - bmin, 0), DIM - 1);
            const int lk = min(max(base[2] + k - bmin, 0), DIM - 1);
            const float4 g = *(const float4*)(gbase +
                ((size_t)((li * DIM + lj) * DIM + lk)) * 4);
            const float gx = g.x, gy = g.y, gz = g.z;   // already velocities
            const float dwx = dw[0][i] *  w[1][j] *  w[2][k] * INV_DXF;
            const float dwy =  w[0][i] * dw[1][j] *  w[2][k] * INV_DXF;
            const float dwz =  w[0][i] *  w[1][j] * dw[2][k] * INV_DXF;
            nF[0] += gx * dwx; nF[1] += gx * dwy; nF[2] += gx * dwz;
            nF[3] += gy * dwx; nF[4] += gy * dwy; nF[5] += gy * dwz;
            nF[6] += gz * dwx; nF[7] += gz * dwy; nF[8] += gz * dwz;
        }
        // butterfly reduce across the particle's 4 lanes
#pragma unroll
        for (int d = 1; d < 4; d <<= 1) {
#pragma unroll
            for (int r = 0; r < 9; ++r) nF[r] += __shfl_xor(nF[r], d, 64);
        }

        if (q == 0) {
            const float* pF  = F + (((size_t)b * T + t)     * Np + n) * 9;
            const float* pFn = F + (((size_t)b * T + t + 1) * Np + n) * 9;
            float Fm[9], Fn[9];
#pragma unroll
            for (int i = 0; i < 9; ++i) { Fm[i] = pF[i]; Fn[i] = pFn[i]; }
#pragma unroll
            for (int a = 0; a < 3; ++a) {
#pragma unroll
                for (int c = 0; c < 3; ++c) {
                    const float fp = Fm[a * 3 + c] + dT *
                        (nF[a * 3 + 0] * Fm[0 + c] +
                         nF[a * 3 + 1] * Fm[3 + c] +
                         nF[a * 3 + 2] * Fm[6 + c]);
                    s += fabsf(fp - Fn[a * 3 + c]);
                }
            }
            s *= (float)TS / ((float)M * (float)Np * 9.0f);
        }
    }

    // block reduction -> per-block partial (plain store)
#pragma unroll
    for (int o = 32; o > 0; o >>= 1) s += __shfl_down(s, o, 64);
    __shared__ float wsum[4];
    const int lane = threadIdx.x & 63;
    const int wid  = threadIdx.x >> 6;
    if (lane == 0) wsum[wid] = s;
    __syncthreads();
    if (threadIdx.x == 0)
        partials[blockIdx.x] = wsum[0] + wsum[1] + wsum[2] + wsum[3];
}

// ---------------- final reduce ---------------------------------------------
__global__ __launch_bounds__(256)
void reduce_kernel(const float* __restrict__ partials, int n,
                   float* __restrict__ out)
{
    float s = 0.0f;
    for (int i = threadIdx.x; i < n; i += 256) s += partials[i];
#pragma unroll
    for (int o = 32; o > 0; o >>= 1) s += __shfl_down(s, o, 64);
    __shared__ float wsum[4];
    const int lane = threadIdx.x & 63;
    const int wid  = threadIdx.x >> 6;
    if (lane == 0) wsum[wid] = s;
    __syncthreads();
    if (threadIdx.x == 0) out[0] = wsum[0] + wsum[1] + wsum[2] + wsum[3];
}

extern "C" void kernel_launch(void* const* d_in, const int* in_sizes, int n_in,
                              void* d_out, int out_size, void* d_ws, size_t ws_size,
                              hipStream_t stream) {
    const float* x   = (const float*)d_in[0];
    const float* vol = (const float*)d_in[1];
    const float* F   = (const float*)d_in[2];
    const float* C   = (const float*)d_in[3];
    const int*   fi  = (const int*)d_in[4];
    const int*   nf  = (const int*)d_in[5];

    const int Np = 2048;
    const int bs = in_sizes[1] / Np;                 // 2
    const int T  = in_sizes[0] / (bs * Np * 3);      // 16
    const int MMAX = bs * (T - 2);                   // 28

    float* grid = (float*)d_ws;
    const size_t grid_f = (size_t)MMAX * DIM3 * 4;   // 14.68 MB
    float* partials = grid + grid_f;

    // P2G: packed f16x2 LDS atomics (2 lane-ops per contribution), fused normalize
    p2g_kernel<<<MMAX * DIM, 1024, 0, stream>>>(x, vol, C, fi, nf,
                                                grid, bs, T, Np);

    // G2P: 4 lanes per particle, per-block partials
    const int nthreads = MMAX * Np * 4;
    const int nblocks  = (nthreads + 255) / 256;     // 3584
    g2p_loss_kernel<<<nblocks, 256, 0, stream>>>(
        x, F, fi, nf, grid, partials, bs, T, Np);

    reduce_kernel<<<1, 256, 0, stream>>>(partials, nblocks, (float*)d_out);
}